// Round 19
// baseline (139.968 us; speedup 1.0000x reference)
//
#include <hip/hip_runtime.h>
#include <stdint.h>
#include <math.h>

// CausalSelfAttention, B=4 N=2048 D=1024, softmax over QUERY axis (axis=1).
// Algebra: S = x Wq^T Wk x^T / 32 = x G x^T / 32.  Gt = Wk^T Wq (tiny);
// H = x (x) Gt replaces BOTH Q and K projections (-1/3 FLOPs).
// Softmax UNstabilized (s ~ N(0,1), exp(s) <= ~150, f32-safe):
// Etilde = exp(s) masked; Z[k] = sum_q Etilde; c[k] = 1/Z; O = Etilde @ (c*V).
// Pipeline: cast_fused (x,Wv linear + Wq,Wk transpose in ONE dispatch) |
//           gemm_g (256 blk 64^2) | proj_all (H, Vt; 512 blk = 2/CU) |
//           gemm_s (Etilde + fused Z partials) |
//           scale_vt_fused (c=1/Z + Vt*=c in ONE dispatch) |
//           gemm_pv v3 (O; 512 blk, 256thr, ratio 0.75).

typedef __attribute__((ext_vector_type(8))) short short8;   // 8 bf16 = 4 VGPR
typedef __attribute__((ext_vector_type(4))) float f32x4;

static __device__ __forceinline__ ushort f2bf(float f) {
  union { float f; uint32_t u; } v; v.f = f;
  uint32_t r = v.u + 0x7FFFu + ((v.u >> 16) & 1u);   // RNE
  return (ushort)(r >> 16);
}
static __device__ __forceinline__ float bf2f(ushort u) {
  union { uint32_t u; float f; } v; v.u = ((uint32_t)u) << 16;
  return v.f;
}

static __device__ __forceinline__ void gload_lds16(const ushort* g, ushort* l) {
  __builtin_amdgcn_global_load_lds(
      (const __attribute__((address_space(1))) void*)g,
      (__attribute__((address_space(3))) void*)l, 16, 0, 0);
}

#define SBAR()   __builtin_amdgcn_s_barrier()
#define SCHED0() __builtin_amdgcn_sched_barrier(0)
#define WAITL0() do { asm volatile("s_waitcnt lgkmcnt(0)" ::: "memory"); SCHED0(); } while (0)
#define WAITV4() asm volatile("s_waitcnt vmcnt(4)" ::: "memory")
#define WAITV3() asm volatile("s_waitcnt vmcnt(3)" ::: "memory")
#define WAITV2() asm volatile("s_waitcnt vmcnt(2)" ::: "memory")
#define WAITV0() asm volatile("s_waitcnt vmcnt(0)" ::: "memory")

// ================= cast_fused: x,Wv linear + Wq,Wk transpose-cast =================
// Grid: n_lin blocks (256 thr, float4 casts) then 512 transpose blocks
// (2 matrices x 16x16 tiles of 64x64).
__global__ void cast_fused(const float* __restrict__ x, const float* __restrict__ Wq,
                           const float* __restrict__ Wk, const float* __restrict__ Wv,
                           ushort* __restrict__ xb, ushort* __restrict__ Wvb,
                           ushort* __restrict__ WqT, ushort* __restrict__ WkT,
                           int n_x4, int n_lin_blocks) {
  __shared__ ushort t[64][65];
  int bid = blockIdx.x;
  int tid = threadIdx.x;
  if (bid < n_lin_blocks) {
    int i = bid * 256 + tid;
    const float* src; ushort* dst; int off;
    if (i < n_x4) { src = x; dst = xb; off = i; }
    else { src = Wv; dst = Wvb; off = i - n_x4; }
    float4 v = ((const float4*)src)[off];
    ushort4 o;
    o.x = f2bf(v.x); o.y = f2bf(v.y); o.z = f2bf(v.z); o.w = f2bf(v.w);
    ((ushort4*)dst)[off] = o;
  } else {
    int rem = bid - n_lin_blocks;                 // 0..511
    const float* src = (rem >= 256) ? Wk : Wq;
    ushort* dst = (rem >= 256) ? WkT : WqT;
    rem &= 255;
    int c0 = (rem & 15) * 64, r0 = (rem >> 4) * 64;
#pragma unroll
    for (int i = 0; i < 16; ++i) {
      int idx = i * 256 + tid, r = idx >> 6, c = idx & 63;
      t[r][c] = f2bf(src[(long)(r0 + r) * 1024 + c0 + c]);
    }
    __syncthreads();
#pragma unroll
    for (int i = 0; i < 16; ++i) {
      int idx = i * 256 + tid, r = idx >> 6, c = idx & 63;
      dst[(long)(c0 + r) * 1024 + r0 + c] = t[c][r];
    }
  }
}

// =====================================================================
// gemm_g: Gt[j][i] = sum_o WkT[j][o] * WqT[i][o]  (1024^2, K=1024).
// 256 blocks of 64x64 (full-chip single round), 4 waves of 32x32,
// 3-buf BK=32 (8KB/buf = 24KB).  UNCHANGED from R18.
// =====================================================================
__global__ __launch_bounds__(256, 3) void gemm_g(
    const ushort* __restrict__ WkT, const ushort* __restrict__ WqT, ushort* __restrict__ Gt)
{
  const int D = 1024;
  const int bm0 = blockIdx.x * 64;
  const int bn0 = blockIdx.y * 64;
  const int nk = 32;

  __shared__ uint4 lds_v[24576 / 16];
  char* lds = (char*)lds_v;

  const int tid  = threadIdx.x;
  const int lane = tid & 63;
  const int wave = tid >> 6;
  const int wr   = wave >> 1;
  const int wc   = wave & 1;
  const int fr   = lane & 15;
  const int fg   = lane >> 4;

  f32x4 acc[2][2];
#pragma unroll
  for (int ii = 0; ii < 2; ++ii)
#pragma unroll
    for (int jj = 0; jj < 2; ++jj) acc[ii][jj] = (f32x4){0.f, 0.f, 0.f, 0.f};

  auto STAGE = [&](int tt) {
    if (tt >= nk) return;
    char* slab = lds + (tt % 3) * 8192;
    {
      int s = tid;
      int row = s >> 2;
      int cc = (s & 3) ^ ((row >> 1) & 3);
      gload_lds16(WkT + (long)(bm0 + row) * D + tt * 32 + cc * 8,
                  (ushort*)(slab + s * 16));
    }
    {
      int s = tid;
      int row = s >> 2;
      int cc = (s & 3) ^ ((row >> 1) & 3);
      gload_lds16(WqT + (long)(bn0 + row) * D + tt * 32 + cc * 8,
                  (ushort*)(slab + 4096 + s * 16));
    }
  };

  STAGE(0); STAGE(1);
  WAITV2();
  SBAR();

  for (int tt = 0; tt < nk; ++tt) {
    char* slab = lds + (tt % 3) * 8192;
    STAGE(tt + 2);
    short8 a[2], bf[2];
#pragma unroll
    for (int ii = 0; ii < 2; ++ii) {
      int row = wr * 32 + ii * 16 + fr;
      int cc = fg ^ ((row >> 1) & 3);
      a[ii] = *(const short8*)(slab + row * 64 + cc * 16);
    }
#pragma unroll
    for (int jj = 0; jj < 2; ++jj) {
      int row = wc * 32 + jj * 16 + fr;
      int cc = fg ^ ((row >> 1) & 3);
      bf[jj] = *(const short8*)(slab + 4096 + row * 64 + cc * 16);
    }
    WAITL0();
    __builtin_amdgcn_s_setprio(1);
#pragma unroll
    for (int ii = 0; ii < 2; ++ii)
#pragma unroll
      for (int jj = 0; jj < 2; ++jj)
        acc[ii][jj] = __builtin_amdgcn_mfma_f32_16x16x32_bf16(a[ii], bf[jj], acc[ii][jj], 0, 0, 0);
    __builtin_amdgcn_s_setprio(0);
    if (tt + 2 < nk) { WAITV2(); } else { WAITV0(); }
    SBAR();
  }

#pragma unroll
  for (int ii = 0; ii < 2; ++ii)
#pragma unroll
    for (int jj = 0; jj < 2; ++jj)
#pragma unroll
      for (int r = 0; r < 4; ++r) {
        int row = bm0 + wr * 32 + ii * 16 + fg * 4 + r;
        int col = bn0 + wc * 32 + jj * 16 + fr;
        Gt[(long)row * D + col] = f2bf(acc[ii][jj][r]);
      }
}

// =====================================================================
// proj_all: H = x (x) Gt  AND  Vt = Wv (x) x^T in ONE dispatch.
// 512 blocks = exactly 2/CU, XCD-chunked.  UNCHANGED (at ceiling).
// =====================================================================
__global__ __launch_bounds__(512, 4) void proj_all(
    const ushort* __restrict__ xb, const ushort* __restrict__ Gt,
    const ushort* __restrict__ Wv, ushort* __restrict__ H, ushort* __restrict__ Vt)
{
  const int D = 1024;
  int L = blockIdx.x;
  L = (L & 7) * 64 + (L >> 3);       // chunked XCD swizzle (bijective)

  const ushort* Ab; const ushort* Bb;
  int bm0, bn0;
  if (L < 256) {
    bm0 = (L >> 3) * 256;
    bn0 = (L & 7) * 128;
    Ab = xb;  Bb = Gt;
  } else {
    int rem = L - 256;
    bm0 = (rem >> 6) * 256;
    bn0 = (rem & 63) * 128;
    Ab = Wv;  Bb = xb;
  }

  const int nk = 32;

  __shared__ uint4 lds_v[73728 / 16];
  char* lds = (char*)lds_v;

  const int tid  = threadIdx.x;
  const int lane = tid & 63;
  const int wave = tid >> 6;
  const int wr   = wave >> 1;
  const int wc   = wave & 1;
  const int fr   = lane & 15;
  const int fg   = lane >> 4;

  f32x4 acc[4][4];
#pragma unroll
  for (int i = 0; i < 4; ++i)
#pragma unroll
    for (int j = 0; j < 4; ++j) acc[i][j] = (f32x4){0.f, 0.f, 0.f, 0.f};

  auto STAGE = [&](int tt) {
    if (tt >= nk) return;
    char* slab = lds + (tt % 3) * 24576;
#pragma unroll
    for (int u = 0; u < 2; ++u) {
      int s = u * 512 + tid;
      int row = s >> 2;
      int cc = (s & 3) ^ ((row >> 1) & 3);
      gload_lds16(Ab + (long)(bm0 + row) * D + tt * 32 + cc * 8,
                  (ushort*)(slab + s * 16));
    }
    {
      int s = tid;
      int row = s >> 2;
      int cc = (s & 3) ^ ((row >> 1) & 3);
      gload_lds16(Bb + (long)(bn0 + row) * D + tt * 32 + cc * 8,
                  (ushort*)(slab + 16384 + s * 16));
    }
  };

  STAGE(0); STAGE(1);
  WAITV3();
  SBAR();

  for (int t = 0; t < nk; ++t) {
    char* slab = lds + (t % 3) * 24576;
    STAGE(t + 2);

    short8 a[4], b[4];
#pragma unroll
    for (int i = 0; i < 4; ++i) {
      int row = wr * 64 + i * 16 + fr;
      int cc = fg ^ ((row >> 1) & 3);
      a[i] = *(const short8*)(slab + row * 64 + cc * 16);
    }
#pragma unroll
    for (int j = 0; j < 4; ++j) {
      int row = wc * 64 + j * 16 + fr;
      int cc = fg ^ ((row >> 1) & 3);
      b[j] = *(const short8*)(slab + 16384 + row * 64 + cc * 16);
    }
    WAITL0();
    __builtin_amdgcn_s_setprio(1);
#pragma unroll
    for (int i = 0; i < 4; ++i)
#pragma unroll
      for (int j = 0; j < 4; ++j)
        acc[i][j] = __builtin_amdgcn_mfma_f32_16x16x32_bf16(a[i], b[j], acc[i][j], 0, 0, 0);
    __builtin_amdgcn_s_setprio(0);

    if (t + 2 < nk) { WAITV3(); } else { WAITV0(); }
    SBAR();
  }

  if (L < 256) {
    ushort* Cb = H;
#pragma unroll
    for (int i = 0; i < 4; ++i)
#pragma unroll
      for (int j = 0; j < 4; ++j)
#pragma unroll
        for (int r = 0; r < 4; ++r) {
          int row = bm0 + wr * 64 + i * 16 + fg * 4 + r;
          int col = bn0 + wc * 64 + j * 16 + fr;
          Cb[(long)row * D + col] = f2bf(acc[i][j][r]);
        }
  } else {
    ushort* Cb = Vt + (long)(bn0 >> 11) * D * 2048;
#pragma unroll
    for (int i = 0; i < 4; ++i)
#pragma unroll
      for (int j = 0; j < 4; ++j)
#pragma unroll
        for (int r = 0; r < 4; ++r) {
          int row = bm0 + wr * 64 + i * 16 + fg * 4 + r;        // d
          int col = (bn0 + wc * 64 + j * 16 + fr) & 2047;       // n within batch
          Cb[(long)row * 2048 + col] = f2bf(acc[i][j][r]);
        }
  }
}

// =====================================================================
// gemm_s: Etilde = exp(H (x) x / 32) masked, lower-triangle 128x128 tiles,
// 544 blocks, XCD-chunked, 3 blocks/CU.  Single-pass fused Z partials.
// UNCHANGED from R18.
// =====================================================================
__global__ __launch_bounds__(256, 3) void gemm_s(
    const ushort* __restrict__ Q, const ushort* __restrict__ Kb, ushort* __restrict__ S,
    float* __restrict__ pZg)
{
  const int NQ = 2048, D = 1024;
  int bid = blockIdx.x;
  bid = (bid & 7) * 68 + (bid >> 3);
  const int b = bid / 136;
  int t = bid - b * 136;
  int i = (int)((sqrtf(8.f * t + 1.f) - 1.f) * 0.5f);
  while ((i + 1) * (i + 2) / 2 <= t) ++i;
  while (i * (i + 1) / 2 > t) --i;
  const int j = t - i * (i + 1) / 2;
  const int bm0 = i * 128;
  const int bn0 = j * 128;

  const ushort* Ab = Q + (long)b * NQ * D;
  const ushort* Bb = Kb + (long)b * NQ * D;

  const int nk = 32;

  __shared__ uint4 lds_v[49152 / 16];
  char* lds = (char*)lds_v;

  const int tid  = threadIdx.x;
  const int lane = tid & 63;
  const int wave = tid >> 6;
  const int wr   = wave >> 1;
  const int wc   = wave & 1;
  const int fr   = lane & 15;
  const int fg   = lane >> 4;

  f32x4 acc[4][4];
#pragma unroll
  for (int ii = 0; ii < 4; ++ii)
#pragma unroll
    for (int jj = 0; jj < 4; ++jj) acc[ii][jj] = (f32x4){0.f, 0.f, 0.f, 0.f};

  auto STAGE = [&](int tt) {
    if (tt >= nk) return;
    char* slab = lds + (tt % 3) * 16384;
#pragma unroll
    for (int u = 0; u < 2; ++u) {
      int s = u * 256 + tid;
      int row = s >> 2;
      int cc = (s & 3) ^ ((row >> 1) & 3);
      gload_lds16(Ab + (long)(bm0 + row) * D + tt * 32 + cc * 8,
                  (ushort*)(slab + s * 16));
    }
#pragma unroll
    for (int u = 0; u < 2; ++u) {
      int s = u * 256 + tid;
      int row = s >> 2;
      int cc = (s & 3) ^ ((row >> 1) & 3);
      gload_lds16(Bb + (long)(bn0 + row) * D + tt * 32 + cc * 8,
                  (ushort*)(slab + 8192 + s * 16));
    }
  };

  STAGE(0); STAGE(1);
  WAITV4();
  SBAR();

  for (int tt = 0; tt < nk; ++tt) {
    char* slab = lds + (tt % 3) * 16384;
    STAGE(tt + 2);

    short8 a[4], bf[4];
#pragma unroll
    for (int ii = 0; ii < 4; ++ii) {
      int row = wr * 64 + ii * 16 + fr;
      int cc = fg ^ ((row >> 1) & 3);
      a[ii] = *(const short8*)(slab + row * 64 + cc * 16);
    }
#pragma unroll
    for (int jj = 0; jj < 4; ++jj) {
      int row = wc * 64 + jj * 16 + fr;
      int cc = fg ^ ((row >> 1) & 3);
      bf[jj] = *(const short8*)(slab + 8192 + row * 64 + cc * 16);
    }
    WAITL0();
    __builtin_amdgcn_s_setprio(1);
#pragma unroll
    for (int ii = 0; ii < 4; ++ii)
#pragma unroll
      for (int jj = 0; jj < 4; ++jj)
        acc[ii][jj] = __builtin_amdgcn_mfma_f32_16x16x32_bf16(a[ii], bf[jj], acc[ii][jj], 0, 0, 0);
    __builtin_amdgcn_s_setprio(0);

    if (tt + 2 < nk) { WAITV4(); } else { WAITV0(); }
    SBAR();
  }

  // ---- epilogue: single pass — write Etilde = exp(s/32) masked, sum Z ----
  ushort* Cb = S + (long)b * NQ * NQ;
  float zcol[4];
#pragma unroll
  for (int jj = 0; jj < 4; ++jj) {
    const int colg = bn0 + wc * 64 + jj * 16 + fr;
    float z = 0.f;
#pragma unroll
    for (int ii = 0; ii < 4; ++ii)
#pragma unroll
      for (int r = 0; r < 4; ++r) {
        int rowg = bm0 + wr * 64 + ii * 16 + fg * 4 + r;
        bool ok = rowg >= colg;
        float e = ok ? __expf(acc[ii][jj][r] * 0.03125f) : 0.f;
        Cb[(long)rowg * NQ + colg] = f2bf(e);
        z += e;
      }
    z += __shfl_xor(z, 16);
    z += __shfl_xor(z, 32);
    zcol[jj] = z;
  }
  float* red = (float*)lds;
  if (fg == 0) {
#pragma unroll
    for (int jj = 0; jj < 4; ++jj)
      red[wr * 128 + wc * 64 + jj * 16 + fr] = zcol[jj];
  }
  SBAR();
  if (wr == 0 && fg == 0) {
#pragma unroll
    for (int jj = 0; jj < 4; ++jj) {
      const int c = wc * 64 + jj * 16 + fr;
      long o = ((long)b * 16 + i) * NQ + bn0 + c;
      pZg[o] = red[c] + red[128 + c];
    }
  }
}

// =====================================================================
// scale_vt_fused: c[k] = 1/(sum over tile-rows i >= k>>7 of pZ[b][i][k]),
// then Vt[b][d][n0..n0+32) *= c for all 1024 d-rows.  ONE dispatch
// replaces colstats_combine + scale_vt.  Grid (64, 4) = 256 blocks.
// =====================================================================
__global__ __launch_bounds__(256) void scale_vt_fused(
    ushort* __restrict__ Vt, const float* __restrict__ pZ)
{
  const int Nq = 2048, Dd = 1024;
  const int b = blockIdx.y;
  const int n0 = blockIdx.x * 32;
  __shared__ float cs[32];
  const int tid = threadIdx.x;
  if (tid < 32) {
    int k = n0 + tid;
    int i0 = k >> 7;
    float Z = 0.f;
    for (int i = i0; i < 16; ++i) Z += pZ[((long)(b * 16 + i)) * Nq + k];
    cs[tid] = 1.0f / Z;
  }
  __syncthreads();
#pragma unroll
  for (int it = 0; it < 16; ++it) {
    int d = it * 64 + (tid >> 2);
    int nn = (tid & 3) * 8;
    ushort* p = Vt + ((long)b * Dd + d) * Nq + n0 + nn;
    union { uint4 v; ushort u[8]; } dv, ov;
    dv.v = *(const uint4*)p;
#pragma unroll
    for (int j = 0; j < 8; ++j) ov.u[j] = f2bf(bf2f(dv.u[j]) * cs[nn + j]);
    *(uint4*)p = ov.v;
  }
}

// =====================================================================
// gemm_pv v3: ratio 0.75.  512 blocks (b x 16 dt x 8 pr), XCD-chunked,
// 256 thr / 4 waves, wave-tile 64(q) x 32(d) (acc 4x2).  2-buf 48KB,
// 3 blocks/CU.  UNCHANGED from R18.
// =====================================================================
__global__ __launch_bounds__(256, 3) void gemm_pv(
    const ushort* __restrict__ P, const ushort* __restrict__ Vt, float* __restrict__ out)
{
  const int NQ = 2048, DD = 1024;
  int L = blockIdx.x;
  L = (L & 7) * 64 + (L >> 3);       // chunked XCD swizzle (bijective)
  const int pr = L & 7, dt = (L >> 3) & 15, b = L >> 7;

  const ushort* Pb = P + (long)b * NQ * NQ;
  const ushort* Vb = Vt + (long)b * DD * NQ + (long)(dt * 64) * NQ;   // 64 d-rows
  float* Ob = out + (long)b * NQ * DD;

  __shared__ uint4 lds_v[49152 / 16];  // 2 x 24KB
  char* lds = (char*)lds_v;

  const int tid  = threadIdx.x;
  const int lane = tid & 63;
  const int wave = tid >> 6;           // 0..3
  const int wr   = wave >> 1;          // 0..1 -> q rows wr*64
  const int wc   = wave & 1;           // 0..1 -> d cols wc*32
  const int fr   = lane & 15;
  const int fg   = lane >> 4;

  for (int h = 0; h < 2; ++h) {
    const int tq = h ? (15 - pr) : pr;
    const int q0 = tq * 128;
    const ushort* Aq = Pb + (long)q0 * NQ;
    const int nk = (tq + 1) * 2;       // K-steps of 64 (nk >= 2)

    f32x4 acc[4][2];
#pragma unroll
    for (int i = 0; i < 4; ++i)
#pragma unroll
      for (int j = 0; j < 2; ++j) acc[i][j] = (f32x4){0.f, 0.f, 0.f, 0.f};

    auto STAGE = [&](int tt) {
      if (tt >= nk) return;
      char* slab = lds + (tt & 1) * 24576;
#pragma unroll
      for (int u = 0; u < 4; ++u) {
        int s = u * 256 + tid;
        int row = s >> 3;
        int cc = (s & 7) ^ (row & 7);
        gload_lds16(Aq + (long)row * NQ + tt * 64 + cc * 8,
                    (ushort*)(slab + s * 16));
      }
#pragma unroll
      for (int u = 0; u < 2; ++u) {
        int s = u * 256 + tid;
        int row = s >> 3;
        int cc = (s & 7) ^ (row & 7);
        gload_lds16(Vb + (long)row * NQ + tt * 64 + cc * 8,
                    (ushort*)(slab + 16384 + s * 16));
      }
    };

    STAGE(0);
    WAITV0();
    SBAR();

    for (int t = 0; t < nk; ++t) {
      char* slab = lds + (t & 1) * 24576;
      STAGE(t + 1);

      short8 a[2][4], bfr[2][2];
#pragma unroll
      for (int kh = 0; kh < 2; ++kh) {
#pragma unroll
        for (int i = 0; i < 4; ++i) {
          int row = wr * 64 + i * 16 + fr;
          int cc = (kh * 4 + fg) ^ (row & 7);
          a[kh][i] = *(const short8*)(slab + row * 128 + cc * 16);
        }
#pragma unroll
        for (int j = 0; j < 2; ++j) {
          int row = wc * 32 + j * 16 + fr;
          int cc = (kh * 4 + fg) ^ (row & 7);
          bfr[kh][j] = *(const short8*)(slab + 16384 + row * 128 + cc * 16);
        }
      }
      WAITL0();
      __builtin_amdgcn_s_setprio(1);
#pragma unroll
      for (int kh = 0; kh < 2; ++kh)
#pragma unroll
        for (int i = 0; i < 4; ++i)
#pragma unroll
          for (int j = 0; j < 2; ++j)
            acc[i][j] = __builtin_amdgcn_mfma_f32_16x16x32_bf16(a[kh][i], bfr[kh][j], acc[i][j], 0, 0, 0);
      __builtin_amdgcn_s_setprio(0);

      WAITV0();
      SBAR();
    }

#pragma unroll
    for (int i = 0; i < 4; ++i)
#pragma unroll
      for (int j = 0; j < 2; ++j)
#pragma unroll
        for (int r = 0; r < 4; ++r) {
          int row = q0 + wr * 64 + i * 16 + fg * 4 + r;
          int col = dt * 64 + wc * 32 + j * 16 + fr;
          Ob[(long)row * DD + col] = acc[i][j][r];
        }
  }
}

// ---------------- launch ----------------
extern "C" void kernel_launch(void* const* d_in, const int* in_sizes, int n_in,
                              void* d_out, int out_size, void* d_ws, size_t ws_size,
                              hipStream_t stream) {
  const float* x  = (const float*)d_in[0];
  const float* Wq = (const float*)d_in[1];
  const float* Wk = (const float*)d_in[2];
  const float* Wv = (const float*)d_in[3];
  float* out = (float*)d_out;

  const int B = 4, N = 2048, D = 1024;
  const long BND = (long)B * N * D;

  char* ws = (char*)d_ws;
  ushort* xb  = (ushort*)ws;                         // [B*N][D] bf16, 16MB
  ushort* WqT = xb + BND;                            // [D][D] bf16 transposed, 2MB
  ushort* WkT = WqT + (long)D * D;                   // 2MB
  ushort* Wvb = WkT + (long)D * D;                   // [D][D] bf16, 2MB
  ushort* Gt  = Wvb + (long)D * D;                   // [D][D] bf16, 2MB
  ushort* Hb  = Gt + (long)D * D;                    // [B*N][D] bf16, 16MB
  ushort* Vt  = Hb + BND;                            // [B][D][N] bf16, 16MB
  ushort* S   = Vt + BND;                            // [B][N][N] bf16 (Etilde), 32MB
  float*  pZ  = (float*)(S + (long)B * N * N);       // [B][16][N] f32

  // K0: all casts (linear + transpose) in ONE dispatch
  {
    int n_x4 = (int)(BND / 4);                       // 2097152
    int n_w4 = D * D / 4;                            // 262144
    int n_lin = (n_x4 + n_w4) / 256;                 // 9216
    cast_fused<<<n_lin + 512, 256, 0, stream>>>(x, Wq, Wk, Wv, xb, Wvb, WqT, WkT,
                                                n_x4, n_lin);
  }

  // K0c: Gt = WkT (x) WqT — 256 x 64^2 blocks, full-chip single round
  {
    dim3 g(16, 16);
    gemm_g<<<g, 256, 0, stream>>>(WkT, WqT, Gt);
  }

  // K1: H = x (x) Gt  AND  Vt = Wv (x) x^T — 512 blocks = 2/CU
  proj_all<<<512, 512, 0, stream>>>(xb, Gt, Wvb, Hb, Vt);

  // K3: Etilde = exp(H (x) x / 32) masked + fused Z partials
  gemm_s<<<544, 256, 0, stream>>>(Hb, xb, S, pZ);

  // K4: c = 1/Z + Vt *= c in ONE dispatch
  {
    dim3 g(N / 32, B);
    scale_vt_fused<<<g, 256, 0, stream>>>(Vt, pZ);
  }

  // K5: O = Etilde @ Vt' — gemm_pv v3 (ratio 0.75, 3 blocks/CU)
  gemm_pv<<<512, 256, 0, stream>>>(S, Vt, out);
}

// Round 20
// 138.309 us; speedup vs baseline: 1.0120x; 1.0120x over previous
//
#include <hip/hip_runtime.h>
#include <stdint.h>
#include <math.h>

// CausalSelfAttention, B=4 N=2048 D=1024, softmax over QUERY axis (axis=1).
// Algebra: S = x Wq^T Wk x^T / 32 = x G x^T / 32.  Gt = Wk^T Wq (tiny);
// H = x (x) Gt replaces BOTH Q and K projections (-1/3 FLOPs).
// Softmax UNstabilized (s ~ N(0,1), exp(s) <= ~150, f32-safe):
// Etilde = exp(s) masked; Z[k] = sum_q Etilde; c[k] = 1/Z; O = Etilde @ (c*V).
// Pipeline (R18-proven structure): cast_all | cast_w_t | gemm_g |
//   proj_all (H, Vt) | gemm_s (Etilde + Z partials) | combine | scale_vt |
//   gemm_pv v4 (3-buf counted vmcnt(6), never drains mid-loop).

typedef __attribute__((ext_vector_type(8))) short short8;   // 8 bf16 = 4 VGPR
typedef __attribute__((ext_vector_type(4))) float f32x4;

static __device__ __forceinline__ ushort f2bf(float f) {
  union { float f; uint32_t u; } v; v.f = f;
  uint32_t r = v.u + 0x7FFFu + ((v.u >> 16) & 1u);   // RNE
  return (ushort)(r >> 16);
}
static __device__ __forceinline__ float bf2f(ushort u) {
  union { uint32_t u; float f; } v; v.u = ((uint32_t)u) << 16;
  return v.f;
}

static __device__ __forceinline__ void gload_lds16(const ushort* g, ushort* l) {
  __builtin_amdgcn_global_load_lds(
      (const __attribute__((address_space(1))) void*)g,
      (__attribute__((address_space(3))) void*)l, 16, 0, 0);
}

#define SBAR()   __builtin_amdgcn_s_barrier()
#define SCHED0() __builtin_amdgcn_sched_barrier(0)
#define WAITL0() do { asm volatile("s_waitcnt lgkmcnt(0)" ::: "memory"); SCHED0(); } while (0)
#define WAITV6() asm volatile("s_waitcnt vmcnt(6)" ::: "memory")
#define WAITV4() asm volatile("s_waitcnt vmcnt(4)" ::: "memory")
#define WAITV3() asm volatile("s_waitcnt vmcnt(3)" ::: "memory")
#define WAITV2() asm volatile("s_waitcnt vmcnt(2)" ::: "memory")
#define WAITV0() asm volatile("s_waitcnt vmcnt(0)" ::: "memory")

// ---------------- cast x + Wv (one dispatch) ----------------
__global__ void cast_all(const float* __restrict__ x, const float* __restrict__ Wv,
                         ushort* __restrict__ xb, ushort* __restrict__ Wvb,
                         int n_x4, int n_w4) {
  int i = blockIdx.x * blockDim.x + threadIdx.x;
  const float* src; ushort* dst; int off;
  if (i < n_x4) { src = x; dst = xb; off = i; }
  else { src = Wv; dst = Wvb; off = i - n_x4; }
  float4 v = ((const float4*)src)[off];
  ushort4 o;
  o.x = f2bf(v.x); o.y = f2bf(v.y); o.z = f2bf(v.z); o.w = f2bf(v.w);
  ((ushort4*)dst)[off] = o;
}

// ---------------- transpose-cast Wq, Wk (f32 [1024][1024] -> bf16 ^T) ----------------
__global__ void cast_w_t(const float* __restrict__ Wq, const float* __restrict__ Wk,
                         ushort* __restrict__ WqT, ushort* __restrict__ WkT) {
  __shared__ ushort t[64][65];
  const float* src = blockIdx.z ? Wk : Wq;
  ushort* dst = blockIdx.z ? WkT : WqT;
  int c0 = blockIdx.x * 64, r0 = blockIdx.y * 64;
  int tid = threadIdx.x;
#pragma unroll
  for (int i = 0; i < 16; ++i) {
    int idx = i * 256 + tid, r = idx >> 6, c = idx & 63;
    t[r][c] = f2bf(src[(long)(r0 + r) * 1024 + c0 + c]);
  }
  __syncthreads();
#pragma unroll
  for (int i = 0; i < 16; ++i) {
    int idx = i * 256 + tid, r = idx >> 6, c = idx & 63;
    dst[(long)(c0 + r) * 1024 + r0 + c] = t[c][r];
  }
}

// =====================================================================
// gemm_g: Gt[j][i] = sum_o WkT[j][o] * WqT[i][o]  (1024^2, K=1024).
// 256 blocks of 64x64 (full-chip single round), 4 waves of 32x32,
// 3-buf BK=32 (8KB/buf = 24KB).
// =====================================================================
__global__ __launch_bounds__(256, 3) void gemm_g(
    const ushort* __restrict__ WkT, const ushort* __restrict__ WqT, ushort* __restrict__ Gt)
{
  const int D = 1024;
  const int bm0 = blockIdx.x * 64;
  const int bn0 = blockIdx.y * 64;
  const int nk = 32;

  __shared__ uint4 lds_v[24576 / 16];
  char* lds = (char*)lds_v;

  const int tid  = threadIdx.x;
  const int lane = tid & 63;
  const int wave = tid >> 6;
  const int wr   = wave >> 1;
  const int wc   = wave & 1;
  const int fr   = lane & 15;
  const int fg   = lane >> 4;

  f32x4 acc[2][2];
#pragma unroll
  for (int ii = 0; ii < 2; ++ii)
#pragma unroll
    for (int jj = 0; jj < 2; ++jj) acc[ii][jj] = (f32x4){0.f, 0.f, 0.f, 0.f};

  auto STAGE = [&](int tt) {
    if (tt >= nk) return;
    char* slab = lds + (tt % 3) * 8192;
    {
      int s = tid;
      int row = s >> 2;
      int cc = (s & 3) ^ ((row >> 1) & 3);
      gload_lds16(WkT + (long)(bm0 + row) * D + tt * 32 + cc * 8,
                  (ushort*)(slab + s * 16));
    }
    {
      int s = tid;
      int row = s >> 2;
      int cc = (s & 3) ^ ((row >> 1) & 3);
      gload_lds16(WqT + (long)(bn0 + row) * D + tt * 32 + cc * 8,
                  (ushort*)(slab + 4096 + s * 16));
    }
  };

  STAGE(0); STAGE(1);
  WAITV2();
  SBAR();

  for (int tt = 0; tt < nk; ++tt) {
    char* slab = lds + (tt % 3) * 8192;
    STAGE(tt + 2);
    short8 a[2], bf[2];
#pragma unroll
    for (int ii = 0; ii < 2; ++ii) {
      int row = wr * 32 + ii * 16 + fr;
      int cc = fg ^ ((row >> 1) & 3);
      a[ii] = *(const short8*)(slab + row * 64 + cc * 16);
    }
#pragma unroll
    for (int jj = 0; jj < 2; ++jj) {
      int row = wc * 32 + jj * 16 + fr;
      int cc = fg ^ ((row >> 1) & 3);
      bf[jj] = *(const short8*)(slab + 4096 + row * 64 + cc * 16);
    }
    WAITL0();
    __builtin_amdgcn_s_setprio(1);
#pragma unroll
    for (int ii = 0; ii < 2; ++ii)
#pragma unroll
      for (int jj = 0; jj < 2; ++jj)
        acc[ii][jj] = __builtin_amdgcn_mfma_f32_16x16x32_bf16(a[ii], bf[jj], acc[ii][jj], 0, 0, 0);
    __builtin_amdgcn_s_setprio(0);
    if (tt + 2 < nk) { WAITV2(); } else { WAITV0(); }
    SBAR();
  }

#pragma unroll
  for (int ii = 0; ii < 2; ++ii)
#pragma unroll
    for (int jj = 0; jj < 2; ++jj)
#pragma unroll
      for (int r = 0; r < 4; ++r) {
        int row = bm0 + wr * 32 + ii * 16 + fg * 4 + r;
        int col = bn0 + wc * 32 + jj * 16 + fr;
        Gt[(long)row * D + col] = f2bf(acc[ii][jj][r]);
      }
}

// =====================================================================
// proj_all: H = x (x) Gt  AND  Vt = Wv (x) x^T in ONE dispatch.
// 512 blocks = exactly 2/CU, XCD-chunked.  UNCHANGED (at ceiling).
// =====================================================================
__global__ __launch_bounds__(512, 4) void proj_all(
    const ushort* __restrict__ xb, const ushort* __restrict__ Gt,
    const ushort* __restrict__ Wv, ushort* __restrict__ H, ushort* __restrict__ Vt)
{
  const int D = 1024;
  int L = blockIdx.x;
  L = (L & 7) * 64 + (L >> 3);       // chunked XCD swizzle (bijective)

  const ushort* Ab; const ushort* Bb;
  int bm0, bn0;
  if (L < 256) {
    bm0 = (L >> 3) * 256;
    bn0 = (L & 7) * 128;
    Ab = xb;  Bb = Gt;
  } else {
    int rem = L - 256;
    bm0 = (rem >> 6) * 256;
    bn0 = (rem & 63) * 128;
    Ab = Wv;  Bb = xb;
  }

  const int nk = 32;

  __shared__ uint4 lds_v[73728 / 16];
  char* lds = (char*)lds_v;

  const int tid  = threadIdx.x;
  const int lane = tid & 63;
  const int wave = tid >> 6;
  const int wr   = wave >> 1;
  const int wc   = wave & 1;
  const int fr   = lane & 15;
  const int fg   = lane >> 4;

  f32x4 acc[4][4];
#pragma unroll
  for (int i = 0; i < 4; ++i)
#pragma unroll
    for (int j = 0; j < 4; ++j) acc[i][j] = (f32x4){0.f, 0.f, 0.f, 0.f};

  auto STAGE = [&](int tt) {
    if (tt >= nk) return;
    char* slab = lds + (tt % 3) * 24576;
#pragma unroll
    for (int u = 0; u < 2; ++u) {
      int s = u * 512 + tid;
      int row = s >> 2;
      int cc = (s & 3) ^ ((row >> 1) & 3);
      gload_lds16(Ab + (long)(bm0 + row) * D + tt * 32 + cc * 8,
                  (ushort*)(slab + s * 16));
    }
    {
      int s = tid;
      int row = s >> 2;
      int cc = (s & 3) ^ ((row >> 1) & 3);
      gload_lds16(Bb + (long)(bn0 + row) * D + tt * 32 + cc * 8,
                  (ushort*)(slab + 16384 + s * 16));
    }
  };

  STAGE(0); STAGE(1);
  WAITV3();
  SBAR();

  for (int t = 0; t < nk; ++t) {
    char* slab = lds + (t % 3) * 24576;
    STAGE(t + 2);

    short8 a[4], b[4];
#pragma unroll
    for (int i = 0; i < 4; ++i) {
      int row = wr * 64 + i * 16 + fr;
      int cc = fg ^ ((row >> 1) & 3);
      a[i] = *(const short8*)(slab + row * 64 + cc * 16);
    }
#pragma unroll
    for (int j = 0; j < 4; ++j) {
      int row = wc * 64 + j * 16 + fr;
      int cc = fg ^ ((row >> 1) & 3);
      b[j] = *(const short8*)(slab + 16384 + row * 64 + cc * 16);
    }
    WAITL0();
    __builtin_amdgcn_s_setprio(1);
#pragma unroll
    for (int i = 0; i < 4; ++i)
#pragma unroll
      for (int j = 0; j < 4; ++j)
        acc[i][j] = __builtin_amdgcn_mfma_f32_16x16x32_bf16(a[i], b[j], acc[i][j], 0, 0, 0);
    __builtin_amdgcn_s_setprio(0);

    if (t + 2 < nk) { WAITV3(); } else { WAITV0(); }
    SBAR();
  }

  if (L < 256) {
    ushort* Cb = H;
#pragma unroll
    for (int i = 0; i < 4; ++i)
#pragma unroll
      for (int j = 0; j < 4; ++j)
#pragma unroll
        for (int r = 0; r < 4; ++r) {
          int row = bm0 + wr * 64 + i * 16 + fg * 4 + r;
          int col = bn0 + wc * 64 + j * 16 + fr;
          Cb[(long)row * D + col] = f2bf(acc[i][j][r]);
        }
  } else {
    ushort* Cb = Vt + (long)(bn0 >> 11) * D * 2048;
#pragma unroll
    for (int i = 0; i < 4; ++i)
#pragma unroll
      for (int j = 0; j < 4; ++j)
#pragma unroll
        for (int r = 0; r < 4; ++r) {
          int row = bm0 + wr * 64 + i * 16 + fg * 4 + r;        // d
          int col = (bn0 + wc * 64 + j * 16 + fr) & 2047;       // n within batch
          Cb[(long)row * 2048 + col] = f2bf(acc[i][j][r]);
        }
  }
}

// =====================================================================
// gemm_s: Etilde = exp(H (x) x / 32) masked, lower-triangle 128x128 tiles,
// 544 blocks, XCD-chunked, 3 blocks/CU.  Single-pass fused Z partials.
// =====================================================================
__global__ __launch_bounds__(256, 3) void gemm_s(
    const ushort* __restrict__ Q, const ushort* __restrict__ Kb, ushort* __restrict__ S,
    float* __restrict__ pZg)
{
  const int NQ = 2048, D = 1024;
  int bid = blockIdx.x;
  bid = (bid & 7) * 68 + (bid >> 3);
  const int b = bid / 136;
  int t = bid - b * 136;
  int i = (int)((sqrtf(8.f * t + 1.f) - 1.f) * 0.5f);
  while ((i + 1) * (i + 2) / 2 <= t) ++i;
  while (i * (i + 1) / 2 > t) --i;
  const int j = t - i * (i + 1) / 2;
  const int bm0 = i * 128;
  const int bn0 = j * 128;

  const ushort* Ab = Q + (long)b * NQ * D;
  const ushort* Bb = Kb + (long)b * NQ * D;

  const int nk = 32;

  __shared__ uint4 lds_v[49152 / 16];
  char* lds = (char*)lds_v;

  const int tid  = threadIdx.x;
  const int lane = tid & 63;
  const int wave = tid >> 6;
  const int wr   = wave >> 1;
  const int wc   = wave & 1;
  const int fr   = lane & 15;
  const int fg   = lane >> 4;

  f32x4 acc[4][4];
#pragma unroll
  for (int ii = 0; ii < 4; ++ii)
#pragma unroll
    for (int jj = 0; jj < 4; ++jj) acc[ii][jj] = (f32x4){0.f, 0.f, 0.f, 0.f};

  auto STAGE = [&](int tt) {
    if (tt >= nk) return;
    char* slab = lds + (tt % 3) * 16384;
#pragma unroll
    for (int u = 0; u < 2; ++u) {
      int s = u * 256 + tid;
      int row = s >> 2;
      int cc = (s & 3) ^ ((row >> 1) & 3);
      gload_lds16(Ab + (long)(bm0 + row) * D + tt * 32 + cc * 8,
                  (ushort*)(slab + s * 16));
    }
#pragma unroll
    for (int u = 0; u < 2; ++u) {
      int s = u * 256 + tid;
      int row = s >> 2;
      int cc = (s & 3) ^ ((row >> 1) & 3);
      gload_lds16(Bb + (long)(bn0 + row) * D + tt * 32 + cc * 8,
                  (ushort*)(slab + 8192 + s * 16));
    }
  };

  STAGE(0); STAGE(1);
  WAITV4();
  SBAR();

  for (int tt = 0; tt < nk; ++tt) {
    char* slab = lds + (tt % 3) * 16384;
    STAGE(tt + 2);

    short8 a[4], bf[4];
#pragma unroll
    for (int ii = 0; ii < 4; ++ii) {
      int row = wr * 64 + ii * 16 + fr;
      int cc = fg ^ ((row >> 1) & 3);
      a[ii] = *(const short8*)(slab + row * 64 + cc * 16);
    }
#pragma unroll
    for (int jj = 0; jj < 4; ++jj) {
      int row = wc * 64 + jj * 16 + fr;
      int cc = fg ^ ((row >> 1) & 3);
      bf[jj] = *(const short8*)(slab + 8192 + row * 64 + cc * 16);
    }
    WAITL0();
    __builtin_amdgcn_s_setprio(1);
#pragma unroll
    for (int ii = 0; ii < 4; ++ii)
#pragma unroll
      for (int jj = 0; jj < 4; ++jj)
        acc[ii][jj] = __builtin_amdgcn_mfma_f32_16x16x32_bf16(a[ii], bf[jj], acc[ii][jj], 0, 0, 0);
    __builtin_amdgcn_s_setprio(0);

    if (tt + 2 < nk) { WAITV4(); } else { WAITV0(); }
    SBAR();
  }

  // ---- epilogue: single pass — write Etilde = exp(s/32) masked, sum Z ----
  ushort* Cb = S + (long)b * NQ * NQ;
  float zcol[4];
#pragma unroll
  for (int jj = 0; jj < 4; ++jj) {
    const int colg = bn0 + wc * 64 + jj * 16 + fr;
    float z = 0.f;
#pragma unroll
    for (int ii = 0; ii < 4; ++ii)
#pragma unroll
      for (int r = 0; r < 4; ++r) {
        int rowg = bm0 + wr * 64 + ii * 16 + fg * 4 + r;
        bool ok = rowg >= colg;
        float e = ok ? __expf(acc[ii][jj][r] * 0.03125f) : 0.f;
        Cb[(long)rowg * NQ + colg] = f2bf(e);
        z += e;
      }
    z += __shfl_xor(z, 16);
    z += __shfl_xor(z, 32);
    zcol[jj] = z;
  }
  float* red = (float*)lds;
  if (fg == 0) {
#pragma unroll
    for (int jj = 0; jj < 4; ++jj)
      red[wr * 128 + wc * 64 + jj * 16 + fr] = zcol[jj];
  }
  SBAR();
  if (wr == 0 && fg == 0) {
#pragma unroll
    for (int jj = 0; jj < 4; ++jj) {
      const int c = wc * 64 + jj * 16 + fr;
      long o = ((long)b * 16 + i) * NQ + bn0 + c;
      pZg[o] = red[c] + red[128 + c];
    }
  }
}

// ---------------- combine: Z = sum over tile-rows i in [k>>7, 16); c = 1/Z ----------------
__global__ void colstats_combine(const float* __restrict__ pZ, float* __restrict__ cvec,
                                 int Nq) {
  int idx = blockIdx.x * 256 + threadIdx.x;
  int b = idx / Nq, k = idx - b * Nq;
  const int i0 = k >> 7;
  const float* PZ = pZ + (long)b * 16 * Nq + k;
  float Z = 0.f;
  for (int c = i0; c < 16; ++c) Z += PZ[(long)c * Nq];
  cvec[idx] = 1.0f / Z;
}

// ---------------- Vt[b][d][n] *= c[b][n] ----------------
__global__ void scale_vt(ushort* __restrict__ Vt, const float* __restrict__ cvec,
                         int Nq, int Dd) {
  long t = (long)blockIdx.x * 256 + threadIdx.x;
  long nrow = t / (Nq / 8);
  int nb = (int)(t % (Nq / 8)) * 8;
  int b = (int)(nrow / Dd);
  ushort* p = Vt + nrow * Nq + nb;
  const float* c = cvec + (long)b * Nq + nb;
  union { uint4 v; ushort u[8]; } d, o;
  d.v = *(const uint4*)p;
#pragma unroll
  for (int j = 0; j < 8; ++j) o.u[j] = f2bf(bf2f(d.u[j]) * c[j]);
  *(uint4*)p = o.v;
}

// =====================================================================
// gemm_pv v4: 3-buf counted vmcnt — never drains mid-loop.
// 512 blocks (b x 16 dt x 8 pr), XCD-chunked, 256 thr / 4 waves,
// wave-tile 64(q) x 32(d) (acc 4x2).  3-buf LDS {A 16KB + V 8KB} x 3
// = 72KB -> 2 blocks/CU.  STAGE(t+2), vmcnt(6): each staged tile has
// ~2 iterations of flight (> HBM latency); drain only at tail.
// Swizzle: 8-chunk rows, chunk c stored at c ^ (row&7) (verified).
// =====================================================================
__global__ __launch_bounds__(256, 2) void gemm_pv(
    const ushort* __restrict__ P, const ushort* __restrict__ Vt, float* __restrict__ out)
{
  const int NQ = 2048, DD = 1024;
  int L = blockIdx.x;
  L = (L & 7) * 64 + (L >> 3);       // chunked XCD swizzle (bijective)
  const int pr = L & 7, dt = (L >> 3) & 15, b = L >> 7;

  const ushort* Pb = P + (long)b * NQ * NQ;
  const ushort* Vb = Vt + (long)b * DD * NQ + (long)(dt * 64) * NQ;   // 64 d-rows
  float* Ob = out + (long)b * NQ * DD;

  __shared__ uint4 lds_v[73728 / 16];  // 3 x 24KB
  char* lds = (char*)lds_v;

  const int tid  = threadIdx.x;
  const int lane = tid & 63;
  const int wave = tid >> 6;           // 0..3
  const int wr   = wave >> 1;          // 0..1 -> q rows wr*64
  const int wc   = wave & 1;           // 0..1 -> d cols wc*32
  const int fr   = lane & 15;
  const int fg   = lane >> 4;

  for (int h = 0; h < 2; ++h) {
    const int tq = h ? (15 - pr) : pr;
    const int q0 = tq * 128;
    const ushort* Aq = Pb + (long)q0 * NQ;
    const int nk = (tq + 1) * 2;       // K-steps of 64 (nk >= 2)

    f32x4 acc[4][2];
#pragma unroll
    for (int i = 0; i < 4; ++i)
#pragma unroll
      for (int j = 0; j < 2; ++j) acc[i][j] = (f32x4){0.f, 0.f, 0.f, 0.f};

    // per buffer: A[128][64] 16KB @0, V[64][64] 8KB @16384; 6 loads/thread
    auto STAGE = [&](int tt) {
      if (tt >= nk) return;
      char* slab = lds + (tt % 3) * 24576;
#pragma unroll
      for (int u = 0; u < 4; ++u) {
        int s = u * 256 + tid;                  // 0..1023
        int row = s >> 3;                       // 0..127
        int cc = (s & 7) ^ (row & 7);
        gload_lds16(Aq + (long)row * NQ + tt * 64 + cc * 8,
                    (ushort*)(slab + s * 16));
      }
#pragma unroll
      for (int u = 0; u < 2; ++u) {
        int s = u * 256 + tid;                  // 0..511
        int row = s >> 3;                       // 0..63
        int cc = (s & 7) ^ (row & 7);
        gload_lds16(Vb + (long)row * NQ + tt * 64 + cc * 8,
                    (ushort*)(slab + 16384 + s * 16));
      }
    };

    STAGE(0); STAGE(1);                // 12 loads in flight
    WAITV6();                          // t0's 6 landed
    SBAR();

    for (int t = 0; t < nk; ++t) {
      char* slab = lds + (t % 3) * 24576;
      STAGE(t + 2);                    // ~2 iterations of flight

      short8 a[2][4], bfr[2][2];
#pragma unroll
      for (int kh = 0; kh < 2; ++kh) {
#pragma unroll
        for (int i = 0; i < 4; ++i) {
          int row = wr * 64 + i * 16 + fr;
          int cc = (kh * 4 + fg) ^ (row & 7);
          a[kh][i] = *(const short8*)(slab + row * 128 + cc * 16);
        }
#pragma unroll
        for (int j = 0; j < 2; ++j) {
          int row = wc * 32 + j * 16 + fr;
          int cc = (kh * 4 + fg) ^ (row & 7);
          bfr[kh][j] = *(const short8*)(slab + 16384 + row * 128 + cc * 16);
        }
      }
      WAITL0();
      __builtin_amdgcn_s_setprio(1);
#pragma unroll
      for (int kh = 0; kh < 2; ++kh)
#pragma unroll
        for (int i = 0; i < 4; ++i)
#pragma unroll
          for (int j = 0; j < 2; ++j)
            acc[i][j] = __builtin_amdgcn_mfma_f32_16x16x32_bf16(a[kh][i], bfr[kh][j], acc[i][j], 0, 0, 0);
      __builtin_amdgcn_s_setprio(0);

      // drain t+1's 6 (keep t+2's 6 in flight); drain fully only at tail
      if (t + 2 < nk)      { WAITV6(); }
      else if (t + 1 < nk) { WAITV0(); }
      SBAR();
    }

    // epilogue: col = lane&15, row = (lane>>4)*4 + r
#pragma unroll
    for (int i = 0; i < 4; ++i)
#pragma unroll
      for (int j = 0; j < 2; ++j)
#pragma unroll
        for (int r = 0; r < 4; ++r) {
          int row = q0 + wr * 64 + i * 16 + fg * 4 + r;
          int col = dt * 64 + wc * 32 + j * 16 + fr;
          Ob[(long)row * DD + col] = acc[i][j][r];
        }
  }
}

// ---------------- launch ----------------
extern "C" void kernel_launch(void* const* d_in, const int* in_sizes, int n_in,
                              void* d_out, int out_size, void* d_ws, size_t ws_size,
                              hipStream_t stream) {
  const float* x  = (const float*)d_in[0];
  const float* Wq = (const float*)d_in[1];
  const float* Wk = (const float*)d_in[2];
  const float* Wv = (const float*)d_in[3];
  float* out = (float*)d_out;

  const int B = 4, N = 2048, D = 1024;
  const long BND = (long)B * N * D;

  char* ws = (char*)d_ws;
  ushort* xb  = (ushort*)ws;                         // [B*N][D] bf16, 16MB
  ushort* WqT = xb + BND;                            // [D][D] bf16 transposed, 2MB
  ushort* WkT = WqT + (long)D * D;                   // 2MB
  ushort* Wvb = WkT + (long)D * D;                   // [D][D] bf16, 2MB
  ushort* Gt  = Wvb + (long)D * D;                   // [D][D] bf16, 2MB
  ushort* Hb  = Gt + (long)D * D;                    // [B*N][D] bf16, 16MB
  ushort* Vt  = Hb + BND;                            // [B][D][N] bf16, 16MB
  ushort* S   = Vt + BND;                            // [B][N][N] bf16 (Etilde), 32MB
  float*  pZ  = (float*)(S + (long)B * N * N);       // [B][16][N] f32
  float*  cv  = pZ + (long)B * 16 * N;               // [B][N] f32

  // K0a: cast x + Wv
  {
    int n_x4 = (int)(BND / 4);
    int n_w4 = D * D / 4;
    cast_all<<<(n_x4 + n_w4) / 256, 256, 0, stream>>>(x, Wv, xb, Wvb, n_x4, n_w4);
  }
  // K0b: transpose-cast Wq, Wk
  {
    dim3 g(16, 16, 2);
    cast_w_t<<<g, 256, 0, stream>>>(Wq, Wk, WqT, WkT);
  }

  // K0c: Gt = WkT (x) WqT — 256 x 64^2 blocks, full-chip single round
  {
    dim3 g(16, 16);
    gemm_g<<<g, 256, 0, stream>>>(WkT, WqT, Gt);
  }

  // K1: H = x (x) Gt  AND  Vt = Wv (x) x^T — 512 blocks = 2/CU
  proj_all<<<512, 512, 0, stream>>>(xb, Gt, Wvb, Hb, Vt);

  // K3: Etilde = exp(H (x) x / 32) masked + fused Z partials
  gemm_s<<<544, 256, 0, stream>>>(Hb, xb, S, pZ);

  // K3b: combine partials -> c[k] = 1/Z
  colstats_combine<<<(B * N) / 256, 256, 0, stream>>>(pZ, cv, N);

  // K4: fold c into Vt
  scale_vt<<<(int)(BND / 8 / 256), 256, 0, stream>>>(Vt, cv, N, D);

  // K5: O = Etilde @ Vt' — gemm_pv v4 (3-buf, counted vmcnt(6))
  gemm_pv<<<512, 256, 0, stream>>>(S, Vt, out);
}